// Round 14
// baseline (345.073 us; speedup 1.0000x reference)
//
#include <hip/hip_runtime.h>
#include <hip/hip_bf16.h>
#include <stdint.h>

// ---------------------------------------------------------------------------
// TransformerBlock fused forward for MI355X (gfx950).
// Shapes (fixed): B=8 TQ=512 TK=2048 D=1024 H=16 HD=64 NE=4 HID=32 NA=512.
//
// Round 14 (gemm_kv only; rest byte-identical to r13):
//  * A operand direct-to-REGISTER (frag order makes each wave's A-frags
//    per-lane contiguous 16B): kills 4 of 12 ds_reads + 1/3 of LDS staging
//    per step. LDS 72KB -> 48KB (Bk|Bv only) -> 3 blocks/CU. Unroll-by-2
//    with named reg sets aE/aO (static indexing, rule #20). Manual
//    vmcnt(12) at barrier covers B staging; compiler inserts the A-reg
//    waitcnts. Drain last two steps (r10/r12-proven convention).
// ---------------------------------------------------------------------------

#define B_   8
#define TQ_  512
#define TK_  2048
#define D_   1024
#define H_   16
#define HD_  64
#define NE_  4
#define HID_ 32
#define EPSF 1e-6f
#define LOG2E 1.44269504f

typedef __bf16 bf16_t;
typedef __bf16 bf16x8 __attribute__((ext_vector_type(8)));
typedef __bf16 bf16x4 __attribute__((ext_vector_type(4)));
typedef float  f32x4  __attribute__((ext_vector_type(4)));

typedef __attribute__((address_space(1))) void gvoid_t;
typedef __attribute__((address_space(3))) void lvoid_t;

__device__ __forceinline__ void gld_lds16(const void* g, void* l) {
  __builtin_amdgcn_global_load_lds((gvoid_t*)g, (lvoid_t*)l, 16, 0, 0);
}

// frag-order address helpers -------------------------------------------------
__device__ __forceinline__ size_t frag64(int row, int d) {
  return (size_t)(row >> 6) * 65536 + (size_t)(d >> 5) * 2048 +
         ((row >> 5) & 1) * 1024 + ((row >> 4) & 1) * 512 +
         ((((d >> 3) & 3) * 16 + (row & 15)) << 3) + (d & 7);
}
__device__ __forceinline__ size_t frag128k(int row, int k, int tns) {
  return (size_t)(row >> 7) * tns + (size_t)(k >> 5) * 4096 +
         ((row >> 6) & 1) * 2048 + ((row >> 4) & 3) * 512 +
         ((((k >> 3) & 3) * 16 + (row & 15)) << 3) + (k & 7);
}

// ---------------------------------------------------------------------------
// Frag-order weight converters (fp32 -> bf16, 128-col frag order).
// ---------------------------------------------------------------------------
struct FP4 { const float* in[4]; bf16_t* out[4]; };

__global__ void fragorder4_kernel(FP4 p) {
  __shared__ float tile[32][33];
  const float* inp = p.in[blockIdx.z];
  bf16_t* out = p.out[blockIdx.z];
  const int rb = blockIdx.y * 32, cb = blockIdx.x * 32;
  const int tx = threadIdx.x, ty = threadIdx.y;
#pragma unroll
  for (int i = 0; i < 32; i += 8)
    tile[ty + i][tx] = inp[(size_t)(rb + ty + i) * D_ + cb + tx];
  __syncthreads();
  const int t = ty * 32 + tx;
  const int n_l = t >> 3;
  const int k_l = (t & 7) * 4;
  const int n = cb + n_l;
  const int k = rb + k_l;
  bf16x4 o;
#pragma unroll
  for (int c = 0; c < 4; ++c) o[c] = (bf16_t)tile[k_l + c][n_l];
  const size_t addr = (size_t)(n >> 7) * 131072 + (size_t)(k >> 5) * 4096 +
                      ((n >> 6) & 1) * 2048 + ((n >> 4) & 3) * 512 +
                      ((((k >> 3) & 3) * 16 + (n & 15)) << 3) + (k & 7);
  *(bf16x4*)&out[addr] = o;
}

__global__ void fragorder_kernel(const float* __restrict__ in, bf16_t* __restrict__ out,
                                 int C, int in_bstride, int obn, int obk, int tns) {
  __shared__ float tile[32][33];
  const int bz = blockIdx.z;
  const float* inp = in + (size_t)bz * in_bstride;
  const int rb = blockIdx.y * 32, cb = blockIdx.x * 32;
  const int tx = threadIdx.x, ty = threadIdx.y;
#pragma unroll
  for (int i = 0; i < 32; i += 8)
    tile[ty + i][tx] = inp[(size_t)(rb + ty + i) * C + cb + tx];
  __syncthreads();
  const int t = ty * 32 + tx;
  const int n_l = t >> 3;
  const int k_l = (t & 7) * 4;
  const int n = cb + n_l + bz * obn;
  const int k = rb + k_l + bz * obk;
  bf16x4 o;
#pragma unroll
  for (int c = 0; c < 4; ++c) o[c] = (bf16_t)tile[k_l + c][n_l];
  const size_t addr = (size_t)(n >> 7) * tns + (size_t)(k >> 5) * 4096 +
                      ((n >> 6) & 1) * 2048 + ((n >> 4) & 3) * 512 +
                      ((((k >> 3) & 3) * 16 + (n & 15)) << 3) + (k & 7);
  *(bf16x4*)&out[addr] = o;
}

__device__ __forceinline__ float block_rsum(float v, float* red) {
  v += __shfl_xor(v, 1);  v += __shfl_xor(v, 2);  v += __shfl_xor(v, 4);
  v += __shfl_xor(v, 8);  v += __shfl_xor(v, 16); v += __shfl_xor(v, 32);
  const int tid = threadIdx.x;
  if ((tid & 63) == 0) red[tid >> 6] = v;
  __syncthreads();
  return red[0] + red[1] + red[2] + red[3];
}

// ---------------------------------------------------------------------------
// RMSNorm of kv -> kvb (frag128 K=1024), xn (frag64), probs.
// ---------------------------------------------------------------------------
__global__ __launch_bounds__(256)
void rms_kv_kernel(const float* __restrict__ kv, const float* __restrict__ kva_w,
                   const float* __restrict__ kvi_w, const float* __restrict__ fn_w,
                   const float* __restrict__ ab, const float* __restrict__ ib,
                   const int* __restrict__ n_act, const float* __restrict__ Wr,
                   const float* __restrict__ br,
                   bf16_t* __restrict__ kvb, bf16_t* __restrict__ xn,
                   float* __restrict__ probs) {
  __shared__ float red[4];
  __shared__ f32x4 pred[4];
  const int row = blockIdx.x;
  const int t = row & (TK_ - 1);
  const int tid = threadIdx.x;
  const float* src = kv + (size_t)row * D_;
  f32x4 v = ((const f32x4*)src)[tid];
  float ss = v[0]*v[0] + v[1]*v[1] + v[2]*v[2] + v[3]*v[3];
  ss = block_rsum(ss, red);
  const float rs = rsqrtf(ss * (1.0f / D_) + EPSF);
  const int Na = n_act[0];
  const float* wsel = (t < Na) ? kva_w : kvi_w;
  const float* bsel = (t < Na) ? ab : ib;
  const int d = tid * 4;
  f32x4 wv = *(const f32x4*)(wsel + d);
  f32x4 bv = *(const f32x4*)(bsel + d);
  f32x4 fv = *(const f32x4*)(fn_w + d);
  bf16x4 o0, o1;
  f32x4 p4 = {};
#pragma unroll
  for (int c = 0; c < 4; ++c) {
    const float xv = v[c] * rs;
    const float xf = xv * fv[c];
    o0[c] = (bf16_t)(xv * wv[c] + bv[c]);
    o1[c] = (bf16_t)xf;
    const f32x4 w4 = *(const f32x4*)&Wr[(d + c) * 4];
    p4 += w4 * xf;
  }
  *(bf16x4*)&kvb[frag128k(row, d, 131072)] = o0;
  *(bf16x4*)&xn[frag64(row, d)] = o1;
#pragma unroll
  for (int m = 1; m <= 32; m <<= 1) {
    p4[0] += __shfl_xor(p4[0], m); p4[1] += __shfl_xor(p4[1], m);
    p4[2] += __shfl_xor(p4[2], m); p4[3] += __shfl_xor(p4[3], m);
  }
  if ((tid & 63) == 0) pred[tid >> 6] = p4;
  __syncthreads();
  if (tid == 0) {
    f32x4 s = pred[0] + pred[1] + pred[2] + pred[3];
    s[0] += br[0]; s[1] += br[1]; s[2] += br[2]; s[3] += br[3];
    const float mx = fmaxf(fmaxf(s[0], s[1]), fmaxf(s[2], s[3]));
    const float e0 = __expf(s[0] - mx), e1 = __expf(s[1] - mx);
    const float e2 = __expf(s[2] - mx), e3 = __expf(s[3] - mx);
    const float inv = 1.0f / (e0 + e1 + e2 + e3);
    f32x4 pr = { e0 * inv, e1 * inv, e2 * inv, e3 * inv };
    *(f32x4*)&probs[row * 4] = pr;
  }
}

__global__ __launch_bounds__(256)
void rms_q_kernel(const float* __restrict__ q, const float* __restrict__ qn_w,
                  bf16_t* __restrict__ qn) {
  __shared__ float red[4];
  const int row = blockIdx.x;
  const int tid = threadIdx.x;
  const float* src = q + (size_t)row * D_;
  f32x4 v = ((const f32x4*)src)[tid];
  float ss = v[0]*v[0] + v[1]*v[1] + v[2]*v[2] + v[3]*v[3];
  ss = block_rsum(ss, red);
  const float rs = rsqrtf(ss * (1.0f / D_) + EPSF);
  const int d = tid * 4;
  f32x4 wv = *(const f32x4*)(qn_w + d);
  bf16x4 o0;
#pragma unroll
  for (int c = 0; c < 4; ++c) o0[c] = (bf16_t)(v[c] * rs * wv[c]);
  *(bf16x4*)&qn[frag64(row, d)] = o0;
}

__device__ __forceinline__ int xcd_swz(int bx, int gx) {
  if ((gx & 7) == 0) { const int cpx = gx >> 3; return (bx & 7) * cpx + (bx >> 3); }
  return bx;
}

// ---------------------------------------------------------------------------
// FUSED K+V projection GEMM: A in REGISTERS (frag-ordered, per-lane 16B),
// Bk/Bv via LDS (3 bufs x 16KB = 48KB -> 3 blocks/CU), counted-vmcnt
// pipeline. Unroll-by-2 with named A-reg sets aE/aO.
// Per step: vmcnt(12) [B(s) done; B/A of s+1 in flight] -> s_barrier ->
// ds_read B -> MFMA(a set, B) -> STAGEB(s+2) + LOADA(s+2 -> freed set).
// ---------------------------------------------------------------------------
__global__ __launch_bounds__(256)
void gemm_kv(const bf16_t* __restrict__ A, const bf16_t* __restrict__ Wk,
             const bf16_t* __restrict__ Wv, const float* __restrict__ bk,
             const float* __restrict__ bv, bf16_t* __restrict__ Kout,
             bf16_t* __restrict__ Vt) {
  __shared__ alignas(16) bf16_t lds[3 * 8192];   // 3 bufs x (Bk 8KB | Bv 8KB)
  const int tid = threadIdx.x;
  const int lane = tid & 63;
  const int w = tid >> 6;
  const int wr = w >> 1, wc = w & 1;
  const int lane15 = lane & 15, lgrp = lane >> 4;

  const int flat = blockIdx.x;
  const int xcd = flat & 7;
  const int local = flat >> 3;
  const int tg = local >> 3;
  const int yy = local & 7;
  const int m0 = (xcd * 16 + tg) * 128;
  const int n0 = yy * 128;

  f32x4 acc_k[4][4] = {};
  f32x4 acc_v[4][4] = {};

  const bf16_t* ga = A  + (size_t)(m0 >> 7) * 131072 + wr * 2048 + lane * 8;
  const bf16_t* gk = Wk + (size_t)(n0 >> 7) * 131072 + tid * 8;
  const bf16_t* gv = Wv + (size_t)(n0 >> 7) * 131072 + tid * 8;

  auto STAGEB = [&](int s) {
    bf16_t* dst = lds + (s % 3) * 8192 + tid * 8;
    const size_t so = (size_t)s * 4096;
    gld_lds16(gk + so,        dst);
    gld_lds16(gk + so + 2048, dst + 2048);
    gld_lds16(gv + so,        dst + 4096);
    gld_lds16(gv + so + 2048, dst + 6144);
  };

  bf16x8 aE[4], aO[4];
  STAGEB(0);
  STAGEB(1);
#pragma unroll
  for (int i = 0; i < 4; ++i) aE[i] = *(const bf16x8*)&ga[i * 512];
#pragma unroll
  for (int i = 0; i < 4; ++i) aO[i] = *(const bf16x8*)&ga[4096 + i * 512];

  const int bbase = wc * 2048 + lane * 8;

#pragma unroll 1
  for (int s = 0; s < 32; s += 2) {
    // ---- EVEN step s (uses aE) ----
    if (s < 30) asm volatile("s_waitcnt vmcnt(12)" ::: "memory");
    else        asm volatile("s_waitcnt vmcnt(0)" ::: "memory");
    __builtin_amdgcn_s_barrier();
    __builtin_amdgcn_sched_barrier(0);
    {
      const bf16_t* buf = lds + (s % 3) * 8192;
      bf16x8 bkf[4], bvf[4];
#pragma unroll
      for (int j = 0; j < 4; ++j) bkf[j] = *(const bf16x8*)&buf[bbase + j * 512];
#pragma unroll
      for (int j = 0; j < 4; ++j) bvf[j] = *(const bf16x8*)&buf[4096 + bbase + j * 512];
      __builtin_amdgcn_s_setprio(1);
#pragma unroll
      for (int i = 0; i < 4; ++i)
#pragma unroll
        for (int j = 0; j < 4; ++j) {
          acc_k[i][j] = __builtin_amdgcn_mfma_f32_16x16x32_bf16(aE[i], bkf[j], acc_k[i][j], 0, 0, 0);
          acc_v[i][j] = __builtin_amdgcn_mfma_f32_16x16x32_bf16(aE[i], bvf[j], acc_v[i][j], 0, 0, 0);
        }
      __builtin_amdgcn_s_setprio(0);
      if (s + 2 < 32) {
        STAGEB(s + 2);
        const size_t so = (size_t)(s + 2) * 4096;
#pragma unroll
        for (int i = 0; i < 4; ++i) aE[i] = *(const bf16x8*)&ga[so + i * 512];
      }
    }
    // ---- ODD step s+1 (uses aO) ----
    if (s + 1 < 30) asm volatile("s_waitcnt vmcnt(12)" ::: "memory");
    else            asm volatile("s_waitcnt vmcnt(0)" ::: "memory");
    __builtin_amdgcn_s_barrier();
    __builtin_amdgcn_sched_barrier(0);
    {
      const bf16_t* buf = lds + ((s + 1) % 3) * 8192;
      bf16x8 bkf[4], bvf[4];
#pragma unroll
      for (int j = 0; j < 4; ++j) bkf[j] = *(const bf16x8*)&buf[bbase + j * 512];
#pragma unroll
      for (int j = 0; j < 4; ++j) bvf[j] = *(const bf16x8*)&buf[4096 + bbase + j * 512];
      __builtin_amdgcn_s_setprio(1);
#pragma unroll
      for (int i = 0; i < 4; ++i)
#pragma unroll
        for (int j = 0; j < 4; ++j) {
          acc_k[i][j] = __builtin_amdgcn_mfma_f32_16x16x32_bf16(aO[i], bkf[j], acc_k[i][j], 0, 0, 0);
          acc_v[i][j] = __builtin_amdgcn_mfma_f32_16x16x32_bf16(aO[i], bvf[j], acc_v[i][j], 0, 0, 0);
        }
      __builtin_amdgcn_s_setprio(0);
      if (s + 3 < 32) {
        STAGEB(s + 3);
        const size_t so = (size_t)(s + 3) * 4096;
#pragma unroll
        for (int i = 0; i < 4; ++i) aO[i] = *(const bf16x8*)&ga[so + i * 512];
      }
    }
  }

  // K epilogue: Kout[tok][n]
  const int row0 = m0 + wr * 64 + (lgrp << 2);
  const int col0 = n0 + wc * 64 + lane15;
#pragma unroll
  for (int j = 0; j < 4; ++j) {
    const int cc = col0 + j * 16;
    const float bkv = bk[cc];
#pragma unroll
    for (int i = 0; i < 4; ++i) {
      const int rr = row0 + i * 16;
#pragma unroll
      for (int r = 0; r < 4; ++r)
        Kout[(size_t)(rr + r) * D_ + cc] = (bf16_t)(acc_k[i][j][r] + bkv);
    }
  }

  // V epilogue: packed transpose via LDS, write vt[b][n][tok]
  __syncthreads();
  bf16_t* vt_l = lds + w * 4608;         // 4 waves x 4608 = 18432 elems < 24576
#pragma unroll
  for (int j = 0; j < 4; ++j) {
    const int nl = j * 16 + lane15;
    const float bvv = bv[n0 + wc * 64 + nl];
#pragma unroll
    for (int i = 0; i < 4; ++i) {
      bf16x4 pv;
#pragma unroll
      for (int r = 0; r < 4; ++r) pv[r] = (bf16_t)(acc_v[i][j][r] + bvv);
      *(bf16x4*)&vt_l[nl * 72 + i * 16 + lgrp * 4] = pv;
    }
  }
  const int bidx2 = m0 >> 11;
  const int tok0 = (m0 & (TK_ - 1)) + wr * 64;
  bf16_t* vbase = Vt + (size_t)bidx2 * D_ * TK_ + (size_t)(n0 + wc * 64) * TK_ + tok0;
#pragma unroll
  for (int it = 0; it < 8; ++it) {
    const int ln = (lane >> 3) + it * 8;
    const int tk = (lane & 7) * 8;
    const bf16x8 v8 = *(const bf16x8*)&vt_l[ln * 72 + tk];
    *(bf16x8*)&vbase[(size_t)ln * TK_ + tk] = v8;
  }
}

// ---------------------------------------------------------------------------
// Pipelined 64x128 GEMM mainloop (frag64 A, frag128 B, K=1024); drain s>=30.
// ---------------------------------------------------------------------------
__device__ __forceinline__ void gemm64p_loop(const bf16_t* __restrict__ ga,
                                             const bf16_t* __restrict__ gb,
                                             bf16_t* lds, int tid, int wr, int wc,
                                             int lane, f32x4 acc[2][4]) {
  auto STAGE = [&](int s) {
    bf16_t* dst = lds + (s % 3) * 6144 + tid * 8;
    const size_t so2 = (size_t)s * 2048;
    const size_t so4 = (size_t)s * 4096;
    gld_lds16(ga + so2,        dst);
    gld_lds16(gb + so4,        dst + 2048);
    gld_lds16(gb + so4 + 2048, dst + 4096);
  };
  STAGE(0);
  STAGE(1);
  const int abase = wr * 1024 + lane * 8;
  const int bbase = 2048 + wc * 2048 + lane * 8;
  for (int s = 0; s < 32; ++s) {
    if (s < 30) asm volatile("s_waitcnt vmcnt(3)" ::: "memory");
    else        asm volatile("s_waitcnt vmcnt(0)" ::: "memory");
    __builtin_amdgcn_s_barrier();
    __builtin_amdgcn_sched_barrier(0);
    const bf16_t* buf = lds + (s % 3) * 6144;
    bf16x8 af[2], bfr[4];
#pragma unroll
    for (int i = 0; i < 2; ++i) af[i]  = *(const bf16x8*)&buf[abase + i * 512];
#pragma unroll
    for (int j = 0; j < 4; ++j) bfr[j] = *(const bf16x8*)&buf[bbase + j * 512];
    if (s + 2 < 32) STAGE(s + 2);
    __builtin_amdgcn_s_setprio(1);
#pragma unroll
    for (int i = 0; i < 2; ++i)
#pragma unroll
      for (int j = 0; j < 4; ++j)
        acc[i][j] = __builtin_amdgcn_mfma_f32_16x16x32_bf16(af[i], bfr[j], acc[i][j], 0, 0, 0);
    __builtin_amdgcn_s_setprio(0);
  }
}

// qp / proj: C row-major (+bias[N]).
template<int HAS_BIAS>
__global__ __launch_bounds__(256)
void gemm64p_tn(const bf16_t* __restrict__ A, const bf16_t* __restrict__ Wt,
                const float* __restrict__ bias, bf16_t* __restrict__ C, int N) {
  __shared__ alignas(16) bf16_t lds[3 * 6144];
  const int tid = threadIdx.x;
  const int lane = tid & 63;
  const int w = tid >> 6;
  const int wr = w >> 1, wc = w & 1;
  const int m0 = xcd_swz(blockIdx.x, gridDim.x) * 64;
  const int n0 = blockIdx.y * 128;
  f32x4 acc[2][4] = {};
  const bf16_t* ga = A  + (size_t)(m0 >> 6) * 65536 + tid * 8;
  const bf16_t* gb = Wt + (size_t)(n0 >> 7) * 131072 + tid * 8;
  gemm64p_loop(ga, gb, lds, tid, wr, wc, lane, acc);
  const int row0 = m0 + wr * 32 + ((lane >> 4) << 2);
  const int col0 = n0 + wc * 64 + (lane & 15);
#pragma unroll
  for (int j = 0; j < 4; ++j) {
    const int cc = col0 + j * 16;
    const float bv = HAS_BIAS ? bias[cc] : 0.0f;
#pragma unroll
    for (int i = 0; i < 2; ++i) {
      const int rr = row0 + i * 16;
#pragma unroll
      for (int r = 0; r < 4; ++r)
        C[(size_t)(rr + r) * N + cc] = (bf16_t)(acc[i][j][r] + bv);
    }
  }
}

// h-GEMM: fused bias + SiLU-gate + probs -> a2 (frag128 K=128 layout).
__global__ __launch_bounds__(256)
void gemm64p_h_act(const bf16_t* __restrict__ A, const bf16_t* __restrict__ Wt,
                   const float* __restrict__ bias, const float* __restrict__ probs,
                   bf16_t* __restrict__ a2) {
  __shared__ alignas(16) bf16_t lds[3 * 6144];
  const int tid = threadIdx.x;
  const int lane = tid & 63;
  const int w = tid >> 6;
  const int wr = w >> 1, wc = w & 1;
  const int m0 = xcd_swz(blockIdx.x, gridDim.x) * 64;
  const int n0 = blockIdx.y * 128;
  f32x4 acc[2][4] = {};
  const bf16_t* ga = A  + (size_t)(m0 >> 6) * 65536 + tid * 8;
  const bf16_t* gb = Wt + (size_t)(n0 >> 7) * 131072 + tid * 8;
  gemm64p_loop(ga, gb, lds, tid, wr, wc, lane, acc);
  const int row0 = m0 + wr * 32 + ((lane >> 4) << 2);
  const int hbase = n0 + wc * 64 + (lane & 15);
  const int e = hbase >> 6;
#pragma unroll
  for (int j = 0; j < 2; ++j) {
    const int ch = hbase + j * 16;
    const float bx = bias[ch], bg = bias[ch + 32];
    const int ac = (ch & 63) + e * 32;
#pragma unroll
    for (int i = 0; i < 2; ++i) {
      const int rr = row0 + i * 16;
#pragma unroll
      for (int r = 0; r < 4; ++r) {
        const float xp = acc[i][j][r] + bx;
        const float g  = acc[i][j + 2][r] + bg;
        const float sg = 1.0f / (1.0f + __expf(-g));
        const float pr = probs[(size_t)(rr + r) * 4 + e];
        a2[frag128k(rr + r, ac, 16384)] = (bf16_t)(pr * xp * g * sg);
      }
    }
  }
}

// ---------------------------------------------------------------------------
// moe-GEMM (K=128, frag inputs, pipelined; drain s>=2) + fused kv_new.
// ---------------------------------------------------------------------------
__global__ __launch_bounds__(256)
void gemm_moe_p(const bf16_t* __restrict__ A, const bf16_t* __restrict__ Wt,
                const float* __restrict__ kv, const float* __restrict__ probs,
                const float* __restrict__ b2, const float* __restrict__ gate_ffn,
                float* __restrict__ out) {
  __shared__ alignas(16) bf16_t lds[3 * 8192];
  const int N = D_;
  const int tid = threadIdx.x;
  const int lane = tid & 63;
  const int w = tid >> 6;
  const int wr = w >> 1, wc = w & 1;
  const int m0 = xcd_swz(blockIdx.x, gridDim.x) * 128;
  const int n0 = blockIdx.y * 128;
  f32x4 acc[4][4] = {};
  const bf16_t* ga = A  + (size_t)(m0 >> 7) * 16384 + tid * 8;
  const bf16_t* gb = Wt + (size_t)(n0 >> 7) * 16384 + tid * 8;
  auto STAGE = [&](int s) {
    bf16_t* dst = lds + (s % 3) * 8192 + tid * 8;
    const size_t so = (size_t)s * 4096;
    gld_lds16(ga + so,        dst);
    gld_lds16(ga + so + 2048, dst + 2048);
    gld_lds16(gb + so,        dst + 4096);
    gld_lds16(gb + so + 2048, dst + 6144);
  };
  STAGE(0);
  STAGE(1);
  const int abase = wr * 2048 + lane * 8;
  const int bbase = 4096 + wc * 2048 + lane * 8;
  for (int s = 0; s < 4; ++s) {
    if (s < 2) asm volatile("s_waitcnt vmcnt(4)" ::: "memory");
    else       asm volatile("s_waitcnt vmcnt(0)" ::: "memory");
    __builtin_amdgcn_s_barrier();
    __builtin_amdgcn_sched_barrier(0);
    const bf16_t* buf = lds + (s % 3) * 8192;
    bf16x8 af[4], bfr[4];
#pragma unroll
    for (int i = 0; i < 4; ++i) af[i]  = *(const bf16x8*)&buf[abase + i * 512];
#pragma unroll
    for (int j = 0; j < 4; ++j) bfr[j] = *(const bf16x8*)&buf[bbase + j * 512];
    if (s + 2 < 4) STAGE(s + 2);
    __builtin_amdgcn_s_setprio(1);
#pragma unroll
    for (int i = 0; i < 4; ++i)
#pragma unroll
      for (int j = 0; j < 4; ++j)
        acc[i][j] = __builtin_amdgcn_mfma_f32_16x16x32_bf16(af[i], bfr[j], acc[i][j], 0, 0, 0);
    __builtin_amdgcn_s_setprio(0);
  }

  const float sgf = 1.0f / (1.0f + __expf(-gate_ffn[0]));
  const int row0 = m0 + wr * 64 + ((lane >> 4) << 2);
  const int col0 = n0 + wc * 64 + (lane & 15);
#pragma unroll
  for (int j = 0; j < 4; ++j) {
    const int cc = col0 + j * 16;
    const f32x4 b2v = { b2[0 * D_ + cc], b2[1 * D_ + cc], b2[2 * D_ + cc], b2[3 * D_ + cc] };
#pragma unroll
    for (int i = 0; i < 4; ++i) {
      const int rr = row0 + i * 16;
#pragma unroll
      for (int r = 0; r < 4; ++r) {
        const f32x4 pr = *(const f32x4*)&probs[(size_t)(rr + r) * 4];
        const float bsum = pr[0]*b2v[0] + pr[1]*b2v[1] + pr[2]*b2v[2] + pr[3]*b2v[3];
        out[(size_t)(rr + r) * N + cc] =
            kv[(size_t)(rr + r) * N + cc] + sgf * (acc[i][j][r] + bsum);
      }
    }
  }
}

// ---------------------------------------------------------------------------
// MFMA flash attention, counted-vmcnt pipelined (r13, frozen).
// ---------------------------------------------------------------------------
__global__ __launch_bounds__(256, 2)
void attn_mfma_kernel(const bf16_t* __restrict__ qp, const bf16_t* __restrict__ kb,
                      const bf16_t* __restrict__ vt, bf16_t* __restrict__ attno,
                      const float* __restrict__ log_temp, const int* __restrict__ n_act) {
  __shared__ alignas(16) bf16_t Ks[3][64 * 64];
  __shared__ alignas(16) bf16_t Vs[3][64 * 64];
  __shared__ alignas(16) bf16_t Ps[4][32 * 64];

  const int dd = blockIdx.x;
  const int xcd = dd & 7, within = dd >> 3;
  const int qt = within & 3, slot0 = within >> 2;
  const int bh = slot0 * 8 + xcd;
  const int b = bh >> 4, h = bh & 15;

  const int tid = threadIdx.x;
  const int lane = tid & 63;
  const int w = tid >> 6;
  const int lane15 = lane & 15, lgrp = lane >> 4, l7 = lane & 7;
  const int Na = n_act[0];
  float temp = __expf(log_temp[0]);
  temp = fminf(fmaxf(temp, 0.1f), 10.0f);
  const float lsc = LOG2E / (64.0f * temp);
  const int rowbase = qt * 128 + w * 32;

  const bf16_t* qsrcA = qp + (size_t)(b * TQ_ + rowbase + lane15) * D_ + h * 64 + lgrp * 8;
  const bf16_t* qsrcB = qsrcA + (size_t)16 * D_;
  bf16x8 qfA0 = *(const bf16x8*)qsrcA;
  bf16x8 qfA1 = *(const bf16x8*)(qsrcA + 32);
  bf16x8 qfB0 = *(const bf16x8*)qsrcB;
  bf16x8 qfB1 = *(const bf16x8*)(qsrcB + 32);
#pragma unroll
  for (int j = 0; j < 8; ++j) {
    qfA0[j] = (bf16_t)((float)qfA0[j] * lsc);
    qfA1[j] = (bf16_t)((float)qfA1[j] * lsc);
    qfB0[j] = (bf16_t)((float)qfB0[j] * lsc);
    qfB1[j] = (bf16_t)((float)qfB1[j] * lsc);
  }

  const int srow = tid >> 3;
  const int schunk = (tid & 7) ^ (srow & 7);
  const bf16_t* ksrc = kb + (size_t)(b * TK_ + srow) * D_ + h * 64 + schunk * 8;
  const bf16_t* vsrc = vt + ((size_t)(b * 16 + h) * 64 + srow) * TK_ + schunk * 8;

  auto STAGE = [&](int t) {
    bf16_t* kd = &Ks[t % 3][tid * 8];
    bf16_t* vd = &Vs[t % 3][tid * 8];
    const bf16_t* kg = ksrc + (size_t)t * 64 * D_;
    const bf16_t* vg = vsrc + (size_t)t * 64;
    gld_lds16(kg,            kd);
    gld_lds16(kg + 32 * D_,  kd + 2048);
    gld_lds16(vg,            vd);
    gld_lds16(vg + 32 * TK_, vd + 2048);
  };

  f32x4 oA[4] = {}, oB[4] = {}, outA[4] = {}, outB[4] = {};
  float laccA = 0.f, laccB = 0.f;

  const float inv_sa = rsqrtf((float)(Na > 1 ? Na : 1));
  const int Ni = TK_ - Na;
  const float inv_si = rsqrtf((float)(Ni > 1 ? Ni : 1));

  STAGE(0);
  STAGE(1);

  const int NT = TK_ / 64;
  for (int t = 0; t < NT; ++t) {
    if (t < NT - 2) asm volatile("s_waitcnt vmcnt(4)" ::: "memory");
    else            asm volatile("s_waitcnt vmcnt(0)" ::: "memory");
    __builtin_amdgcn_s_barrier();
    __builtin_amdgcn_sched_barrier(0);
    const bf16_t* Kc = Ks[t % 3];
    const bf16_t* Vc = Vs[t % 3];

    f32x4 sA[4], sB[4];
    __builtin_amdgcn_s_setprio(1);
#pragma unroll
    for (int cf = 0; cf < 4; ++cf) {
      const int krow = (cf * 16 + lane15) * 64;
      const bf16x8 kf0 = *(const bf16x8*)&Kc[krow + ((lgrp ^ l7) << 3)];
      const bf16x8 kf1 = *(const bf16x8*)&Kc[krow + (((lgrp + 4) ^ l7) << 3)];
      f32x4 s = {};
      s = __builtin_amdgcn_mfma_f32_16x16x32_bf16(kf0, qfA0, s, 0, 0, 0);
      s = __builtin_amdgcn_mfma_f32_16x16x32_bf16(kf1, qfA1, s, 0, 0, 0);
      sA[cf] = s;
      f32x4 s2 = {};
      s2 = __builtin_amdgcn_mfma_f32_16x16x32_bf16(kf0, qfB0, s2, 0, 0, 0);
      s2 = __builtin_amdgcn_mfma_f32_16x16x32_bf16(kf1, qfB1, s2, 0, 0, 0);
      sB[cf] = s2;
    }
    __builtin_amdgcn_s_setprio(0);

    if (t + 2 < NT) STAGE(t + 2);

#pragma unroll
    for (int cf = 0; cf < 4; ++cf) {
      const int c = cf * 2 + (lgrp >> 1);
      const int pcol = ((c ^ l7) << 3) + (lgrp & 1) * 4;
      f32x4 pA, pB;
#pragma unroll
      for (int r = 0; r < 4; ++r) pA[r] = exp2f(sA[cf][r]);
#pragma unroll
      for (int r = 0; r < 4; ++r) pB[r] = exp2f(sB[cf][r]);
      laccA += (pA[0] + pA[1]) + (pA[2] + pA[3]);
      laccB += (pB[0] + pB[1]) + (pB[2] + pB[3]);
      bf16x4 pvA, pvB;
#pragma unroll
      for (int r = 0; r < 4; ++r) { pvA[r] = (bf16_t)pA[r]; pvB[r] = (bf16_t)pB[r]; }
      *(bf16x4*)&Ps[w][lane15 * 64 + pcol]        = pvA;
      *(bf16x4*)&Ps[w][(16 + lane15) * 64 + pcol] = pvB;
    }

    {
      const int prowA = lane15 * 64;
      const int prowB = (16 + lane15) * 64;
      const bf16x8 paA0 = *(const bf16x8*)&Ps[w][prowA + ((lgrp ^ l7) << 3)];
      const bf16x8 paA1 = *(const bf16x8*)&Ps[w][prowA + (((lgrp + 4) ^ l7) << 3)];
      const bf16x8 paB0 = *(const bf16x8*)&Ps[w][prowB + ((lgrp ^ l7) << 3)];
      const bf16x8 paB1 = *(const bf16x8*)&Ps[w][prowB + (((lgrp + 4) ^ l7) << 3)];
      __builtin_amdgcn_s_setprio(1);
#pragma unroll
      for (int df = 0; df < 4; ++df) {
        const int vrow = (df * 16 + lane15) * 64;
        const bf16x8 vf0 = *(const bf16x8*)&Vc[vrow + ((lgrp ^ l7) << 3)];
        const bf16x8 vf1 = *(const bf16x8*)&Vc[vrow + (((lgrp + 4) ^ l7) << 3)];
        oA[df] = __builtin_amdgcn_mfma_f32_16x16x32_bf16(paA0, vf0, oA[df], 0, 0, 0);
        oA[df] = __builtin_amdgcn_mfma_f32_16x16x32_bf16(paA1, vf1, oA[df], 0, 0, 0);
        oB[df] = __builtin_amdgcn_mfma_f32_16x16x32_bf16(paB0, vf0, oB[df], 0, 0, 0);
        oB[df] = __builtin_amdgcn_mfma_f32_16x16x32_bf16(paB1, vf1, oB[df], 0, 0, 0);
      }
      __builtin_amdgcn_s_setprio(0);
    }

    const bool endA = ((t + 1) * 64 == Na);
    const bool endI = (t == NT - 1);
    if (endA || endI) {
      float lA = laccA, lB = laccB;
      lA += __shfl_xor(lA, 16); lA += __shfl_xor(lA, 32);
      lB += __shfl_xor(lB, 16); lB += __shfl_xor(lB, 32);
      const float ssc = endA ? inv_sa : -inv_si;
      f32x4 ivA, ivB;
#pragma unroll
      for (int r = 0; r < 4; ++r) {
        ivA[r] = ssc / __shfl(lA, lgrp * 4 + r);
        ivB[r] = ssc / __shfl(lB, lgrp * 4 + r);
      }
#pragma unroll
      for (int df = 0; df < 4; ++df) {
        outA[df] += oA[df] * ivA; oA[df] = (f32x4){};
        outB[df] += oB[df] * ivB; oB[df] = (f32x4){};
      }
      laccA = 0.f; laccB = 0.f;
    }
  }

  // O write in frag64 order (consumed by proj GEMM)
#pragma unroll
  for (int df = 0; df < 4; ++df)
#pragma unroll
    for (int r = 0; r < 4; ++r) {
      const int Rr = b * TQ_ + rowbase + lgrp * 4 + r;
      const int col = h * 64 + df * 16 + lane15;
      attno[frag64(Rr, col)]      = (bf16_t)outA[df][r];
      attno[frag64(Rr + 16, col)] = (bf16_t)outB[df][r];
    }
}

// ---------------------------------------------------------------------------
// delta = rmsnorm(proj, dn_w); q_new = q + sigmoid(gate_attn)*delta (fp32 out)
// ---------------------------------------------------------------------------
__global__ __launch_bounds__(256)
void delta_qnew_kernel(const bf16_t* __restrict__ proj, const float* __restrict__ dn_w,
                       const float* __restrict__ q, const float* __restrict__ gate_attn,
                       float* __restrict__ qnew) {
  __shared__ float red[4];
  const int row = blockIdx.x;
  const int tid = threadIdx.x;
  bf16x4 pv = *(const bf16x4*)(proj + (size_t)row * D_ + tid * 4);
  f32x4 v;
#pragma unroll
  for (int c = 0; c < 4; ++c) v[c] = (float)pv[c];
  float ss = v[0]*v[0] + v[1]*v[1] + v[2]*v[2] + v[3]*v[3];
  ss = block_rsum(ss, red);
  const float rs = rsqrtf(ss * (1.0f / D_) + EPSF);
  const float sga = 1.0f / (1.0f + __expf(-gate_attn[0]));
  const int d = tid * 4;
  f32x4 wv = *(const f32x4*)(dn_w + d);
  f32x4 qv = *(const f32x4*)(q + (size_t)row * D_ + d);
  f32x4 out;
#pragma unroll
  for (int c = 0; c < 4; ++c) out[c] = qv[c] + sga * (v[c] * rs * wv[c]);
  *(f32x4*)&qnew[(size_t)row * D_ + d] = out;
}

// ---------------------------------------------------------------------------
extern "C" void kernel_launch(void* const* d_in, const int* in_sizes, int n_in,
                              void* d_out, int out_size, void* d_ws, size_t ws_size,
                              hipStream_t stream) {
  const float* q           = (const float*)d_in[0];
  const float* kv          = (const float*)d_in[1];
  const float* qn_w        = (const float*)d_in[2];
  const float* kva_w       = (const float*)d_in[3];
  const float* kvi_w       = (const float*)d_in[4];
  const float* dn_w        = (const float*)d_in[5];
  const float* fn_w        = (const float*)d_in[6];
  const float* Wq          = (const float*)d_in[7];
  const float* bq          = (const float*)d_in[8];
  const float* Wk          = (const float*)d_in[9];
  const float* bk          = (const float*)d_in[10];
  const float* Wv          = (const float*)d_in[11];
  const float* bv          = (const float*)d_in[12];
  const float* Wo          = (const float*)d_in[13];
  const float* bo          = (const float*)d_in[14];
  const float* active_bias = (const float*)d_in[15];
  const float* inactive_b  = (const float*)d_in[16];
  const float* log_temp    = (const float*)d_in[17];
  const float* gate_attn   = (const float*)d_in[18];
  const float* gate_ffn    = (const float*)d_in[19];
  const float* Wr          = (const float*)d_in[20];
  const float* br          = (const float*)d_in[21];
  const float* W1          = (const float*)d_in[22];
  const float* b1          = (const float*)d_in[23];
  const float* W2          = (const float*)d_in[24];
  const float* b2          = (const float*)d_in[25];
  const int*   n_act       = (const int*)d_in[27];

  char* ws = (char*)d_ws;
  size_t off = 0;
  auto alloc = [&](size_t bytes) -> char* {
    char* p = ws + off;
    off = (off + bytes + 255) & ~(size_t)255;
    return p;
  };

  bf16_t* wqT  = (bf16_t*)alloc((size_t)D_ * D_ * 2);
  bf16_t* wkT  = (bf16_t*)alloc((size_t)D_ * D_ * 2);
  bf16_t* wvT  = (bf16_t*)alloc((size_t)D_ * D_ * 2);
  bf16_t* woT  = (bf16_t*)alloc((size_t)D_ * D_ * 2);
  bf16_t* w1T  = (bf16_t*)alloc((size_t)256 * D_ * 2);
  bf16_t* w2T  = (bf16_t*)alloc((size_t)D_ * 128 * 2);
  bf16_t* kvb  = (bf16_t*)alloc((size_t)B_ * TK_ * D_ * 2);
  bf16_t* xn   = (bf16_t*)alloc((size_t)B_ * TK_ * D_ * 2);
  bf16_t* qn   = (bf16_t*)alloc((size_t)B_ * TQ_ * D_ * 2);
  bf16_t* qp   = (bf16_t*)alloc((size_t)B_ * TQ_ * D_ * 2);
  bf16_t* kbuf = (bf16_t*)alloc((size_t)B_ * TK_ * D_ * 2);
  bf16_t* vt   = (bf16_t*)alloc((size_t)B_ * D_ * TK_ * 2);
  float*  probs = (float*)alloc((size_t)B_ * TK_ * NE_ * 4);
  bf16_t* attno = qn;
  bf16_t* proj  = qp;
  bf16_t* a2buf = kbuf;
  (void)ws_size; (void)in_sizes; (void)n_in; (void)out_size;

  float* q_new_out  = (float*)d_out;
  float* kv_new_out = (float*)d_out + (size_t)B_ * TQ_ * D_;

  dim3 tb(32, 8);
  FP4 fp;
  fp.in[0] = Wq; fp.in[1] = Wk; fp.in[2] = Wv; fp.in[3] = Wo;
  fp.out[0] = wqT; fp.out[1] = wkT; fp.out[2] = wvT; fp.out[3] = woT;
  fragorder4_kernel<<<dim3(32, 32, 4), tb, 0, stream>>>(fp);
  fragorder_kernel<<<dim3(2, 32, 4), tb, 0, stream>>>(W1, w1T, 64, D_ * 64, 64, 0, 131072);
  fragorder_kernel<<<dim3(32, 1, 4), tb, 0, stream>>>(W2, w2T, D_, 32 * D_, 0, 32, 16384);

  rms_kv_kernel<<<B_ * TK_, 256, 0, stream>>>(kv, kva_w, kvi_w, fn_w, active_bias,
                                              inactive_b, n_act, Wr, br, kvb, xn, probs);
  rms_q_kernel<<<B_ * TQ_, 256, 0, stream>>>(q, qn_w, qn);

  gemm64p_tn<1><<<dim3(B_ * TQ_ / 64, D_ / 128), 256, 0, stream>>>(qn, wqT, bq, qp, D_);
  gemm_kv<<<B_ * TK_ / 128 * (D_ / 128), 256, 0, stream>>>(kvb, wkT, wvT, bk, bv, kbuf, vt);

  attn_mfma_kernel<<<B_ * H_ * (TQ_ / 128), 256, 0, stream>>>(qp, kbuf, vt, attno, log_temp, n_act);

  gemm64p_tn<1><<<dim3(B_ * TQ_ / 64, D_ / 128), 256, 0, stream>>>(attno, woT, bo, proj, D_);
  delta_qnew_kernel<<<B_ * TQ_, 256, 0, stream>>>(proj, dn_w, q, gate_attn, q_new_out);

  gemm64p_h_act<<<dim3(B_ * TK_ / 64, 2), 256, 0, stream>>>(xn, w1T, b1, probs, a2buf);
  gemm_moe_p<<<dim3(B_ * TK_ / 128, D_ / 128), 256, 0, stream>>>(a2buf, w2T, kv, probs, b2,
                                                                 gate_ffn, kv_new_out);
}

// Round 15
// 319.253 us; speedup vs baseline: 1.0809x; 1.0809x over previous
//
#include <hip/hip_runtime.h>
#include <hip/hip_bf16.h>
#include <stdint.h>

// ---------------------------------------------------------------------------
// TransformerBlock fused forward for MI355X (gfx950).
// Shapes (fixed): B=8 TQ=512 TK=2048 D=1024 H=16 HD=64 NE=4 HID=32 NA=512.
//
// Round 15: byte-exact restore of the r13 optimum (319.7us). r14's A-to-
// register experiment regressed gemm_kv 96->121us (T14 reg-staging is
// net-negative where global_load_lds applies; compiler vmcnt deps break the
// counted-vmcnt protocol). All kernels here are r13-identical.
// ---------------------------------------------------------------------------

#define B_   8
#define TQ_  512
#define TK_  2048
#define D_   1024
#define H_   16
#define HD_  64
#define NE_  4
#define HID_ 32
#define EPSF 1e-6f
#define LOG2E 1.44269504f

typedef __bf16 bf16_t;
typedef __bf16 bf16x8 __attribute__((ext_vector_type(8)));
typedef __bf16 bf16x4 __attribute__((ext_vector_type(4)));
typedef float  f32x4  __attribute__((ext_vector_type(4)));

typedef __attribute__((address_space(1))) void gvoid_t;
typedef __attribute__((address_space(3))) void lvoid_t;

__device__ __forceinline__ void gld_lds16(const void* g, void* l) {
  __builtin_amdgcn_global_load_lds((gvoid_t*)g, (lvoid_t*)l, 16, 0, 0);
}

// frag-order address helpers -------------------------------------------------
__device__ __forceinline__ size_t frag64(int row, int d) {
  return (size_t)(row >> 6) * 65536 + (size_t)(d >> 5) * 2048 +
         ((row >> 5) & 1) * 1024 + ((row >> 4) & 1) * 512 +
         ((((d >> 3) & 3) * 16 + (row & 15)) << 3) + (d & 7);
}
__device__ __forceinline__ size_t frag128k(int row, int k, int tns) {
  return (size_t)(row >> 7) * tns + (size_t)(k >> 5) * 4096 +
         ((row >> 6) & 1) * 2048 + ((row >> 4) & 3) * 512 +
         ((((k >> 3) & 3) * 16 + (row & 15)) << 3) + (k & 7);
}

// ---------------------------------------------------------------------------
// Frag-order weight converters (fp32 -> bf16, 128-col frag order).
// ---------------------------------------------------------------------------
struct FP4 { const float* in[4]; bf16_t* out[4]; };

__global__ void fragorder4_kernel(FP4 p) {
  __shared__ float tile[32][33];
  const float* inp = p.in[blockIdx.z];
  bf16_t* out = p.out[blockIdx.z];
  const int rb = blockIdx.y * 32, cb = blockIdx.x * 32;
  const int tx = threadIdx.x, ty = threadIdx.y;
#pragma unroll
  for (int i = 0; i < 32; i += 8)
    tile[ty + i][tx] = inp[(size_t)(rb + ty + i) * D_ + cb + tx];
  __syncthreads();
  const int t = ty * 32 + tx;
  const int n_l = t >> 3;
  const int k_l = (t & 7) * 4;
  const int n = cb + n_l;
  const int k = rb + k_l;
  bf16x4 o;
#pragma unroll
  for (int c = 0; c < 4; ++c) o[c] = (bf16_t)tile[k_l + c][n_l];
  const size_t addr = (size_t)(n >> 7) * 131072 + (size_t)(k >> 5) * 4096 +
                      ((n >> 6) & 1) * 2048 + ((n >> 4) & 3) * 512 +
                      ((((k >> 3) & 3) * 16 + (n & 15)) << 3) + (k & 7);
  *(bf16x4*)&out[addr] = o;
}

__global__ void fragorder_kernel(const float* __restrict__ in, bf16_t* __restrict__ out,
                                 int C, int in_bstride, int obn, int obk, int tns) {
  __shared__ float tile[32][33];
  const int bz = blockIdx.z;
  const float* inp = in + (size_t)bz * in_bstride;
  const int rb = blockIdx.y * 32, cb = blockIdx.x * 32;
  const int tx = threadIdx.x, ty = threadIdx.y;
#pragma unroll
  for (int i = 0; i < 32; i += 8)
    tile[ty + i][tx] = inp[(size_t)(rb + ty + i) * C + cb + tx];
  __syncthreads();
  const int t = ty * 32 + tx;
  const int n_l = t >> 3;
  const int k_l = (t & 7) * 4;
  const int n = cb + n_l + bz * obn;
  const int k = rb + k_l + bz * obk;
  bf16x4 o;
#pragma unroll
  for (int c = 0; c < 4; ++c) o[c] = (bf16_t)tile[k_l + c][n_l];
  const size_t addr = (size_t)(n >> 7) * tns + (size_t)(k >> 5) * 4096 +
                      ((n >> 6) & 1) * 2048 + ((n >> 4) & 3) * 512 +
                      ((((k >> 3) & 3) * 16 + (n & 15)) << 3) + (k & 7);
  *(bf16x4*)&out[addr] = o;
}

__device__ __forceinline__ float block_rsum(float v, float* red) {
  v += __shfl_xor(v, 1);  v += __shfl_xor(v, 2);  v += __shfl_xor(v, 4);
  v += __shfl_xor(v, 8);  v += __shfl_xor(v, 16); v += __shfl_xor(v, 32);
  const int tid = threadIdx.x;
  if ((tid & 63) == 0) red[tid >> 6] = v;
  __syncthreads();
  return red[0] + red[1] + red[2] + red[3];
}

// ---------------------------------------------------------------------------
// RMSNorm of kv -> kvb (frag128 K=1024), xn (frag64), probs.
// ---------------------------------------------------------------------------
__global__ __launch_bounds__(256)
void rms_kv_kernel(const float* __restrict__ kv, const float* __restrict__ kva_w,
                   const float* __restrict__ kvi_w, const float* __restrict__ fn_w,
                   const float* __restrict__ ab, const float* __restrict__ ib,
                   const int* __restrict__ n_act, const float* __restrict__ Wr,
                   const float* __restrict__ br,
                   bf16_t* __restrict__ kvb, bf16_t* __restrict__ xn,
                   float* __restrict__ probs) {
  __shared__ float red[4];
  __shared__ f32x4 pred[4];
  const int row = blockIdx.x;
  const int t = row & (TK_ - 1);
  const int tid = threadIdx.x;
  const float* src = kv + (size_t)row * D_;
  f32x4 v = ((const f32x4*)src)[tid];
  float ss = v[0]*v[0] + v[1]*v[1] + v[2]*v[2] + v[3]*v[3];
  ss = block_rsum(ss, red);
  const float rs = rsqrtf(ss * (1.0f / D_) + EPSF);
  const int Na = n_act[0];
  const float* wsel = (t < Na) ? kva_w : kvi_w;
  const float* bsel = (t < Na) ? ab : ib;
  const int d = tid * 4;
  f32x4 wv = *(const f32x4*)(wsel + d);
  f32x4 bv = *(const f32x4*)(bsel + d);
  f32x4 fv = *(const f32x4*)(fn_w + d);
  bf16x4 o0, o1;
  f32x4 p4 = {};
#pragma unroll
  for (int c = 0; c < 4; ++c) {
    const float xv = v[c] * rs;
    const float xf = xv * fv[c];
    o0[c] = (bf16_t)(xv * wv[c] + bv[c]);
    o1[c] = (bf16_t)xf;
    const f32x4 w4 = *(const f32x4*)&Wr[(d + c) * 4];
    p4 += w4 * xf;
  }
  *(bf16x4*)&kvb[frag128k(row, d, 131072)] = o0;
  *(bf16x4*)&xn[frag64(row, d)] = o1;
#pragma unroll
  for (int m = 1; m <= 32; m <<= 1) {
    p4[0] += __shfl_xor(p4[0], m); p4[1] += __shfl_xor(p4[1], m);
    p4[2] += __shfl_xor(p4[2], m); p4[3] += __shfl_xor(p4[3], m);
  }
  if ((tid & 63) == 0) pred[tid >> 6] = p4;
  __syncthreads();
  if (tid == 0) {
    f32x4 s = pred[0] + pred[1] + pred[2] + pred[3];
    s[0] += br[0]; s[1] += br[1]; s[2] += br[2]; s[3] += br[3];
    const float mx = fmaxf(fmaxf(s[0], s[1]), fmaxf(s[2], s[3]));
    const float e0 = __expf(s[0] - mx), e1 = __expf(s[1] - mx);
    const float e2 = __expf(s[2] - mx), e3 = __expf(s[3] - mx);
    const float inv = 1.0f / (e0 + e1 + e2 + e3);
    f32x4 pr = { e0 * inv, e1 * inv, e2 * inv, e3 * inv };
    *(f32x4*)&probs[row * 4] = pr;
  }
}

__global__ __launch_bounds__(256)
void rms_q_kernel(const float* __restrict__ q, const float* __restrict__ qn_w,
                  bf16_t* __restrict__ qn) {
  __shared__ float red[4];
  const int row = blockIdx.x;
  const int tid = threadIdx.x;
  const float* src = q + (size_t)row * D_;
  f32x4 v = ((const f32x4*)src)[tid];
  float ss = v[0]*v[0] + v[1]*v[1] + v[2]*v[2] + v[3]*v[3];
  ss = block_rsum(ss, red);
  const float rs = rsqrtf(ss * (1.0f / D_) + EPSF);
  const int d = tid * 4;
  f32x4 wv = *(const f32x4*)(qn_w + d);
  bf16x4 o0;
#pragma unroll
  for (int c = 0; c < 4; ++c) o0[c] = (bf16_t)(v[c] * rs * wv[c]);
  *(bf16x4*)&qn[frag64(row, d)] = o0;
}

__device__ __forceinline__ int xcd_swz(int bx, int gx) {
  if ((gx & 7) == 0) { const int cpx = gx >> 3; return (bx & 7) * cpx + (bx >> 3); }
  return bx;
}

// ---------------------------------------------------------------------------
// FUSED K+V projection GEMM (r10/r12-EXACT): frag-ordered inputs, depth-2
// counted-vmcnt pipeline over 3 LDS buffers; drain last TWO steps (s<30).
// ---------------------------------------------------------------------------
__global__ __launch_bounds__(256)
void gemm_kv(const bf16_t* __restrict__ A, const bf16_t* __restrict__ Wk,
             const bf16_t* __restrict__ Wv, const float* __restrict__ bk,
             const float* __restrict__ bv, bf16_t* __restrict__ Kout,
             bf16_t* __restrict__ Vt) {
  __shared__ alignas(16) bf16_t lds[3 * 12288];
  const int tid = threadIdx.x;
  const int lane = tid & 63;
  const int w = tid >> 6;
  const int wr = w >> 1, wc = w & 1;
  const int lane15 = lane & 15, lgrp = lane >> 4;

  const int flat = blockIdx.x;
  const int xcd = flat & 7;
  const int local = flat >> 3;
  const int tg = local >> 3;
  const int yy = local & 7;
  const int m0 = (xcd * 16 + tg) * 128;
  const int n0 = yy * 128;

  f32x4 acc_k[4][4] = {};
  f32x4 acc_v[4][4] = {};

  const bf16_t* ga = A  + (size_t)(m0 >> 7) * 131072 + tid * 8;
  const bf16_t* gk = Wk + (size_t)(n0 >> 7) * 131072 + tid * 8;
  const bf16_t* gv = Wv + (size_t)(n0 >> 7) * 131072 + tid * 8;

  auto STAGE = [&](int s) {
    bf16_t* dst = lds + (s % 3) * 12288 + tid * 8;
    const size_t so = (size_t)s * 4096;
    gld_lds16(ga + so,        dst);
    gld_lds16(ga + so + 2048, dst + 2048);
    gld_lds16(gk + so,        dst + 4096);
    gld_lds16(gk + so + 2048, dst + 6144);
    gld_lds16(gv + so,        dst + 8192);
    gld_lds16(gv + so + 2048, dst + 10240);
  };

  STAGE(0);
  STAGE(1);

  const int abase = wr * 2048 + lane * 8;
  const int bbase = wc * 2048 + lane * 8;
  for (int s = 0; s < 32; ++s) {
    if (s < 30) asm volatile("s_waitcnt vmcnt(6)" ::: "memory");
    else        asm volatile("s_waitcnt vmcnt(0)" ::: "memory");
    __builtin_amdgcn_s_barrier();
    __builtin_amdgcn_sched_barrier(0);
    const bf16_t* buf = lds + (s % 3) * 12288;
    bf16x8 af[4], bkf[4], bvf[4];
#pragma unroll
    for (int i = 0; i < 4; ++i) af[i]  = *(const bf16x8*)&buf[abase + i * 512];
#pragma unroll
    for (int j = 0; j < 4; ++j) bkf[j] = *(const bf16x8*)&buf[4096 + bbase + j * 512];
#pragma unroll
    for (int j = 0; j < 4; ++j) bvf[j] = *(const bf16x8*)&buf[8192 + bbase + j * 512];
    if (s + 2 < 32) STAGE(s + 2);
    __builtin_amdgcn_s_setprio(1);
#pragma unroll
    for (int i = 0; i < 4; ++i)
#pragma unroll
      for (int j = 0; j < 4; ++j) {
        acc_k[i][j] = __builtin_amdgcn_mfma_f32_16x16x32_bf16(af[i], bkf[j], acc_k[i][j], 0, 0, 0);
        acc_v[i][j] = __builtin_amdgcn_mfma_f32_16x16x32_bf16(af[i], bvf[j], acc_v[i][j], 0, 0, 0);
      }
    __builtin_amdgcn_s_setprio(0);
  }

  // K epilogue: Kout[tok][n]
  const int row0 = m0 + wr * 64 + (lgrp << 2);
  const int col0 = n0 + wc * 64 + lane15;
#pragma unroll
  for (int j = 0; j < 4; ++j) {
    const int cc = col0 + j * 16;
    const float bkv = bk[cc];
#pragma unroll
    for (int i = 0; i < 4; ++i) {
      const int rr = row0 + i * 16;
#pragma unroll
      for (int r = 0; r < 4; ++r)
        Kout[(size_t)(rr + r) * D_ + cc] = (bf16_t)(acc_k[i][j][r] + bkv);
    }
  }

  // V epilogue: packed transpose via LDS, write vt[b][n][tok]
  __syncthreads();
  bf16_t* vt_l = lds + w * 4608;
#pragma unroll
  for (int j = 0; j < 4; ++j) {
    const int nl = j * 16 + lane15;
    const float bvv = bv[n0 + wc * 64 + nl];
#pragma unroll
    for (int i = 0; i < 4; ++i) {
      bf16x4 pv;
#pragma unroll
      for (int r = 0; r < 4; ++r) pv[r] = (bf16_t)(acc_v[i][j][r] + bvv);
      *(bf16x4*)&vt_l[nl * 72 + i * 16 + lgrp * 4] = pv;
    }
  }
  const int bidx2 = m0 >> 11;
  const int tok0 = (m0 & (TK_ - 1)) + wr * 64;
  bf16_t* vbase = Vt + (size_t)bidx2 * D_ * TK_ + (size_t)(n0 + wc * 64) * TK_ + tok0;
#pragma unroll
  for (int it = 0; it < 8; ++it) {
    const int ln = (lane >> 3) + it * 8;
    const int tk = (lane & 7) * 8;
    const bf16x8 v8 = *(const bf16x8*)&vt_l[ln * 72 + tk];
    *(bf16x8*)&vbase[(size_t)ln * TK_ + tk] = v8;
  }
}

// ---------------------------------------------------------------------------
// Pipelined 64x128 GEMM mainloop (frag64 A, frag128 B, K=1024); drain s>=30.
// ---------------------------------------------------------------------------
__device__ __forceinline__ void gemm64p_loop(const bf16_t* __restrict__ ga,
                                             const bf16_t* __restrict__ gb,
                                             bf16_t* lds, int tid, int wr, int wc,
                                             int lane, f32x4 acc[2][4]) {
  auto STAGE = [&](int s) {
    bf16_t* dst = lds + (s % 3) * 6144 + tid * 8;
    const size_t so2 = (size_t)s * 2048;
    const size_t so4 = (size_t)s * 4096;
    gld_lds16(ga + so2,        dst);
    gld_lds16(gb + so4,        dst + 2048);
    gld_lds16(gb + so4 + 2048, dst + 4096);
  };
  STAGE(0);
  STAGE(1);
  const int abase = wr * 1024 + lane * 8;
  const int bbase = 2048 + wc * 2048 + lane * 8;
  for (int s = 0; s < 32; ++s) {
    if (s < 30) asm volatile("s_waitcnt vmcnt(3)" ::: "memory");
    else        asm volatile("s_waitcnt vmcnt(0)" ::: "memory");
    __builtin_amdgcn_s_barrier();
    __builtin_amdgcn_sched_barrier(0);
    const bf16_t* buf = lds + (s % 3) * 6144;
    bf16x8 af[2], bfr[4];
#pragma unroll
    for (int i = 0; i < 2; ++i) af[i]  = *(const bf16x8*)&buf[abase + i * 512];
#pragma unroll
    for (int j = 0; j < 4; ++j) bfr[j] = *(const bf16x8*)&buf[bbase + j * 512];
    if (s + 2 < 32) STAGE(s + 2);
    __builtin_amdgcn_s_setprio(1);
#pragma unroll
    for (int i = 0; i < 2; ++i)
#pragma unroll
      for (int j = 0; j < 4; ++j)
        acc[i][j] = __builtin_amdgcn_mfma_f32_16x16x32_bf16(af[i], bfr[j], acc[i][j], 0, 0, 0);
    __builtin_amdgcn_s_setprio(0);
  }
}

// qp / proj: C row-major (+bias[N]).
template<int HAS_BIAS>
__global__ __launch_bounds__(256)
void gemm64p_tn(const bf16_t* __restrict__ A, const bf16_t* __restrict__ Wt,
                const float* __restrict__ bias, bf16_t* __restrict__ C, int N) {
  __shared__ alignas(16) bf16_t lds[3 * 6144];
  const int tid = threadIdx.x;
  const int lane = tid & 63;
  const int w = tid >> 6;
  const int wr = w >> 1, wc = w & 1;
  const int m0 = xcd_swz(blockIdx.x, gridDim.x) * 64;
  const int n0 = blockIdx.y * 128;
  f32x4 acc[2][4] = {};
  const bf16_t* ga = A  + (size_t)(m0 >> 6) * 65536 + tid * 8;
  const bf16_t* gb = Wt + (size_t)(n0 >> 7) * 131072 + tid * 8;
  gemm64p_loop(ga, gb, lds, tid, wr, wc, lane, acc);
  const int row0 = m0 + wr * 32 + ((lane >> 4) << 2);
  const int col0 = n0 + wc * 64 + (lane & 15);
#pragma unroll
  for (int j = 0; j < 4; ++j) {
    const int cc = col0 + j * 16;
    const float bv = HAS_BIAS ? bias[cc] : 0.0f;
#pragma unroll
    for (int i = 0; i < 2; ++i) {
      const int rr = row0 + i * 16;
#pragma unroll
      for (int r = 0; r < 4; ++r)
        C[(size_t)(rr + r) * N + cc] = (bf16_t)(acc[i][j][r] + bv);
    }
  }
}

// h-GEMM: fused bias + SiLU-gate + probs -> a2 (frag128 K=128 layout).
__global__ __launch_bounds__(256)
void gemm64p_h_act(const bf16_t* __restrict__ A, const bf16_t* __restrict__ Wt,
                   const float* __restrict__ bias, const float* __restrict__ probs,
                   bf16_t* __restrict__ a2) {
  __shared__ alignas(16) bf16_t lds[3 * 6144];
  const int tid = threadIdx.x;
  const int lane = tid & 63;
  const int w = tid >> 6;
  const int wr = w >> 1, wc = w & 1;
  const int m0 = xcd_swz(blockIdx.x, gridDim.x) * 64;
  const int n0 = blockIdx.y * 128;
  f32x4 acc[2][4] = {};
  const bf16_t* ga = A  + (size_t)(m0 >> 6) * 65536 + tid * 8;
  const bf16_t* gb = Wt + (size_t)(n0 >> 7) * 131072 + tid * 8;
  gemm64p_loop(ga, gb, lds, tid, wr, wc, lane, acc);
  const int row0 = m0 + wr * 32 + ((lane >> 4) << 2);
  const int hbase = n0 + wc * 64 + (lane & 15);
  const int e = hbase >> 6;
#pragma unroll
  for (int j = 0; j < 2; ++j) {
    const int ch = hbase + j * 16;
    const float bx = bias[ch], bg = bias[ch + 32];
    const int ac = (ch & 63) + e * 32;
#pragma unroll
    for (int i = 0; i < 2; ++i) {
      const int rr = row0 + i * 16;
#pragma unroll
      for (int r = 0; r < 4; ++r) {
        const float xp = acc[i][j][r] + bx;
        const float g  = acc[i][j + 2][r] + bg;
        const float sg = 1.0f / (1.0f + __expf(-g));
        const float pr = probs[(size_t)(rr + r) * 4 + e];
        a2[frag128k(rr + r, ac, 16384)] = (bf16_t)(pr * xp * g * sg);
      }
    }
  }
}

// ---------------------------------------------------------------------------
// moe-GEMM (K=128, frag inputs, pipelined; drain s>=2) + fused kv_new.
// ---------------------------------------------------------------------------
__global__ __launch_bounds__(256)
void gemm_moe_p(const bf16_t* __restrict__ A, const bf16_t* __restrict__ Wt,
                const float* __restrict__ kv, const float* __restrict__ probs,
                const float* __restrict__ b2, const float* __restrict__ gate_ffn,
                float* __restrict__ out) {
  __shared__ alignas(16) bf16_t lds[3 * 8192];
  const int N = D_;
  const int tid = threadIdx.x;
  const int lane = tid & 63;
  const int w = tid >> 6;
  const int wr = w >> 1, wc = w & 1;
  const int m0 = xcd_swz(blockIdx.x, gridDim.x) * 128;
  const int n0 = blockIdx.y * 128;
  f32x4 acc[4][4] = {};
  const bf16_t* ga = A  + (size_t)(m0 >> 7) * 16384 + tid * 8;
  const bf16_t* gb = Wt + (size_t)(n0 >> 7) * 16384 + tid * 8;
  auto STAGE = [&](int s) {
    bf16_t* dst = lds + (s % 3) * 8192 + tid * 8;
    const size_t so = (size_t)s * 4096;
    gld_lds16(ga + so,        dst);
    gld_lds16(ga + so + 2048, dst + 2048);
    gld_lds16(gb + so,        dst + 4096);
    gld_lds16(gb + so + 2048, dst + 6144);
  };
  STAGE(0);
  STAGE(1);
  const int abase = wr * 2048 + lane * 8;
  const int bbase = 4096 + wc * 2048 + lane * 8;
  for (int s = 0; s < 4; ++s) {
    if (s < 2) asm volatile("s_waitcnt vmcnt(4)" ::: "memory");
    else       asm volatile("s_waitcnt vmcnt(0)" ::: "memory");
    __builtin_amdgcn_s_barrier();
    __builtin_amdgcn_sched_barrier(0);
    const bf16_t* buf = lds + (s % 3) * 8192;
    bf16x8 af[4], bfr[4];
#pragma unroll
    for (int i = 0; i < 4; ++i) af[i]  = *(const bf16x8*)&buf[abase + i * 512];
#pragma unroll
    for (int j = 0; j < 4; ++j) bfr[j] = *(const bf16x8*)&buf[bbase + j * 512];
    if (s + 2 < 4) STAGE(s + 2);
    __builtin_amdgcn_s_setprio(1);
#pragma unroll
    for (int i = 0; i < 4; ++i)
#pragma unroll
      for (int j = 0; j < 4; ++j)
        acc[i][j] = __builtin_amdgcn_mfma_f32_16x16x32_bf16(af[i], bfr[j], acc[i][j], 0, 0, 0);
    __builtin_amdgcn_s_setprio(0);
  }

  const float sgf = 1.0f / (1.0f + __expf(-gate_ffn[0]));
  const int row0 = m0 + wr * 64 + ((lane >> 4) << 2);
  const int col0 = n0 + wc * 64 + (lane & 15);
#pragma unroll
  for (int j = 0; j < 4; ++j) {
    const int cc = col0 + j * 16;
    const f32x4 b2v = { b2[0 * D_ + cc], b2[1 * D_ + cc], b2[2 * D_ + cc], b2[3 * D_ + cc] };
#pragma unroll
    for (int i = 0; i < 4; ++i) {
      const int rr = row0 + i * 16;
#pragma unroll
      for (int r = 0; r < 4; ++r) {
        const f32x4 pr = *(const f32x4*)&probs[(size_t)(rr + r) * 4];
        const float bsum = pr[0]*b2v[0] + pr[1]*b2v[1] + pr[2]*b2v[2] + pr[3]*b2v[3];
        out[(size_t)(rr + r) * N + cc] =
            kv[(size_t)(rr + r) * N + cc] + sgf * (acc[i][j][r] + bsum);
      }
    }
  }
}

// ---------------------------------------------------------------------------
// MFMA flash attention, counted-vmcnt pipelined (r13, frozen).
// Block = 256 thr (4 waves) = (b, h, 128 q-rows); wave w: rows w*32..+32 via
// two Q-frag sets. 3 K/V LDS buffers (64KB total), vmcnt(4) per tile.
// ---------------------------------------------------------------------------
__global__ __launch_bounds__(256, 2)
void attn_mfma_kernel(const bf16_t* __restrict__ qp, const bf16_t* __restrict__ kb,
                      const bf16_t* __restrict__ vt, bf16_t* __restrict__ attno,
                      const float* __restrict__ log_temp, const int* __restrict__ n_act) {
  __shared__ alignas(16) bf16_t Ks[3][64 * 64];
  __shared__ alignas(16) bf16_t Vs[3][64 * 64];
  __shared__ alignas(16) bf16_t Ps[4][32 * 64];

  const int dd = blockIdx.x;
  const int xcd = dd & 7, within = dd >> 3;
  const int qt = within & 3, slot0 = within >> 2;
  const int bh = slot0 * 8 + xcd;
  const int b = bh >> 4, h = bh & 15;

  const int tid = threadIdx.x;
  const int lane = tid & 63;
  const int w = tid >> 6;
  const int lane15 = lane & 15, lgrp = lane >> 4, l7 = lane & 7;
  const int Na = n_act[0];
  float temp = __expf(log_temp[0]);
  temp = fminf(fmaxf(temp, 0.1f), 10.0f);
  const float lsc = LOG2E / (64.0f * temp);
  const int rowbase = qt * 128 + w * 32;

  const bf16_t* qsrcA = qp + (size_t)(b * TQ_ + rowbase + lane15) * D_ + h * 64 + lgrp * 8;
  const bf16_t* qsrcB = qsrcA + (size_t)16 * D_;
  bf16x8 qfA0 = *(const bf16x8*)qsrcA;
  bf16x8 qfA1 = *(const bf16x8*)(qsrcA + 32);
  bf16x8 qfB0 = *(const bf16x8*)qsrcB;
  bf16x8 qfB1 = *(const bf16x8*)(qsrcB + 32);
#pragma unroll
  for (int j = 0; j < 8; ++j) {
    qfA0[j] = (bf16_t)((float)qfA0[j] * lsc);
    qfA1[j] = (bf16_t)((float)qfA1[j] * lsc);
    qfB0[j] = (bf16_t)((float)qfB0[j] * lsc);
    qfB1[j] = (bf16_t)((float)qfB1[j] * lsc);
  }

  const int srow = tid >> 3;
  const int schunk = (tid & 7) ^ (srow & 7);
  const bf16_t* ksrc = kb + (size_t)(b * TK_ + srow) * D_ + h * 64 + schunk * 8;
  const bf16_t* vsrc = vt + ((size_t)(b * 16 + h) * 64 + srow) * TK_ + schunk * 8;

  auto STAGE = [&](int t) {
    bf16_t* kd = &Ks[t % 3][tid * 8];
    bf16_t* vd = &Vs[t % 3][tid * 8];
    const bf16_t* kg = ksrc + (size_t)t * 64 * D_;
    const bf16_t* vg = vsrc + (size_t)t * 64;
    gld_lds16(kg,            kd);
    gld_lds16(kg + 32 * D_,  kd + 2048);
    gld_lds16(vg,            vd);
    gld_lds16(vg + 32 * TK_, vd + 2048);
  };

  f32x4 oA[4] = {}, oB[4] = {}, outA[4] = {}, outB[4] = {};
  float laccA = 0.f, laccB = 0.f;

  const float inv_sa = rsqrtf((float)(Na > 1 ? Na : 1));
  const int Ni = TK_ - Na;
  const float inv_si = rsqrtf((float)(Ni > 1 ? Ni : 1));

  STAGE(0);
  STAGE(1);

  const int NT = TK_ / 64;
  for (int t = 0; t < NT; ++t) {
    if (t < NT - 2) asm volatile("s_waitcnt vmcnt(4)" ::: "memory");
    else            asm volatile("s_waitcnt vmcnt(0)" ::: "memory");
    __builtin_amdgcn_s_barrier();
    __builtin_amdgcn_sched_barrier(0);
    const bf16_t* Kc = Ks[t % 3];
    const bf16_t* Vc = Vs[t % 3];

    f32x4 sA[4], sB[4];
    __builtin_amdgcn_s_setprio(1);
#pragma unroll
    for (int cf = 0; cf < 4; ++cf) {
      const int krow = (cf * 16 + lane15) * 64;
      const bf16x8 kf0 = *(const bf16x8*)&Kc[krow + ((lgrp ^ l7) << 3)];
      const bf16x8 kf1 = *(const bf16x8*)&Kc[krow + (((lgrp + 4) ^ l7) << 3)];
      f32x4 s = {};
      s = __builtin_amdgcn_mfma_f32_16x16x32_bf16(kf0, qfA0, s, 0, 0, 0);
      s = __builtin_amdgcn_mfma_f32_16x16x32_bf16(kf1, qfA1, s, 0, 0, 0);
      sA[cf] = s;
      f32x4 s2 = {};
      s2 = __builtin_amdgcn_mfma_f32_16x16x32_bf16(kf0, qfB0, s2, 0, 0, 0);
      s2 = __builtin_amdgcn_mfma_f32_16x16x32_bf16(kf1, qfB1, s2, 0, 0, 0);
      sB[cf] = s2;
    }
    __builtin_amdgcn_s_setprio(0);

    if (t + 2 < NT) STAGE(t + 2);

#pragma unroll
    for (int cf = 0; cf < 4; ++cf) {
      const int c = cf * 2 + (lgrp >> 1);
      const int pcol = ((c ^ l7) << 3) + (lgrp & 1) * 4;
      f32x4 pA, pB;
#pragma unroll
      for (int r = 0; r < 4; ++r) pA[r] = exp2f(sA[cf][r]);
#pragma unroll
      for (int r = 0; r < 4; ++r) pB[r] = exp2f(sB[cf][r]);
      laccA += (pA[0] + pA[1]) + (pA[2] + pA[3]);
      laccB += (pB[0] + pB[1]) + (pB[2] + pB[3]);
      bf16x4 pvA, pvB;
#pragma unroll
      for (int r = 0; r < 4; ++r) { pvA[r] = (bf16_t)pA[r]; pvB[r] = (bf16_t)pB[r]; }
      *(bf16x4*)&Ps[w][lane15 * 64 + pcol]        = pvA;
      *(bf16x4*)&Ps[w][(16 + lane15) * 64 + pcol] = pvB;
    }

    {
      const int prowA = lane15 * 64;
      const int prowB = (16 + lane15) * 64;
      const bf16x8 paA0 = *(const bf16x8*)&Ps[w][prowA + ((lgrp ^ l7) << 3)];
      const bf16x8 paA1 = *(const bf16x8*)&Ps[w][prowA + (((lgrp + 4) ^ l7) << 3)];
      const bf16x8 paB0 = *(const bf16x8*)&Ps[w][prowB + ((lgrp ^ l7) << 3)];
      const bf16x8 paB1 = *(const bf16x8*)&Ps[w][prowB + (((lgrp + 4) ^ l7) << 3)];
      __builtin_amdgcn_s_setprio(1);
#pragma unroll
      for (int df = 0; df < 4; ++df) {
        const int vrow = (df * 16 + lane15) * 64;
        const bf16x8 vf0 = *(const bf16x8*)&Vc[vrow + ((lgrp ^ l7) << 3)];
        const bf16x8 vf1 = *(const bf16x8*)&Vc[vrow + (((lgrp + 4) ^ l7) << 3)];
        oA[df] = __builtin_amdgcn_mfma_f32_16x16x32_bf16(paA0, vf0, oA[df], 0, 0, 0);
        oA[df] = __builtin_amdgcn_mfma_f32_16x16x32_bf16(paA1, vf1, oA[df], 0, 0, 0);
        oB[df] = __builtin_amdgcn_mfma_f32_16x16x32_bf16(paB0, vf0, oB[df], 0, 0, 0);
        oB[df] = __builtin_amdgcn_mfma_f32_16x16x32_bf16(paB1, vf1, oB[df], 0, 0, 0);
      }
      __builtin_amdgcn_s_setprio(0);
    }

    const bool endA = ((t + 1) * 64 == Na);
    const bool endI = (t == NT - 1);
    if (endA || endI) {
      float lA = laccA, lB = laccB;
      lA += __shfl_xor(lA, 16); lA += __shfl_xor(lA, 32);
      lB += __shfl_xor(lB, 16); lB += __shfl_xor(lB, 32);
      const float ssc = endA ? inv_sa : -inv_si;
      f32x4 ivA, ivB;
#pragma unroll
      for (int r = 0; r < 4; ++r) {
        ivA[r] = ssc / __shfl(lA, lgrp * 4 + r);
        ivB[r] = ssc / __shfl(lB, lgrp * 4 + r);
      }
#pragma unroll
      for (int df = 0; df < 4; ++df) {
        outA[df] += oA[df] * ivA; oA[df] = (f32x4){};
        outB[df] += oB[df] * ivB; oB[df] = (f32x4){};
      }
      laccA = 0.f; laccB = 0.f;
    }
  }

  // O write in frag64 order (consumed by proj GEMM)
#pragma unroll
  for (int df = 0; df < 4; ++df)
#pragma unroll
    for (int r = 0; r < 4; ++r) {
      const int Rr = b * TQ_ + rowbase + lgrp * 4 + r;
      const int col = h * 64 + df * 16 + lane15;
      attno[frag64(Rr, col)]      = (bf16_t)outA[df][r];
      attno[frag64(Rr + 16, col)] = (bf16_t)outB[df][r];
    }
}

// ---------------------------------------------------------------------------
// delta = rmsnorm(proj, dn_w); q_new = q + sigmoid(gate_attn)*delta (fp32 out)
// ---------------------------------------------------------------------------
__global__ __launch_bounds__(256)
void delta_qnew_kernel(const bf16_t* __restrict__ proj, const float* __restrict__ dn_w,
                       const float* __restrict__ q, const float* __restrict__ gate_attn,
                       float* __restrict__ qnew) {
  __shared__ float red[4];
  const int row = blockIdx.x;
  const int tid = threadIdx.x;
  bf16x4 pv = *(const bf16x4*)(proj + (size_t)row * D_ + tid * 4);
  f32x4 v;
#pragma unroll
  for (int c = 0; c < 4; ++c) v[c] = (float)pv[c];
  float ss = v[0]*v[0] + v[1]*v[1] + v[2]*v[2] + v[3]*v[3];
  ss = block_rsum(ss, red);
  const float rs = rsqrtf(ss * (1.0f / D_) + EPSF);
  const float sga = 1.0f / (1.0f + __expf(-gate_attn[0]));
  const int d = tid * 4;
  f32x4 wv = *(const f32x4*)(dn_w + d);
  f32x4 qv = *(const f32x4*)(q + (size_t)row * D_ + d);
  f32x4 out;
#pragma unroll
  for (int c = 0; c < 4; ++c) out[c] = qv[c] + sga * (v[c] * rs * wv[c]);
  *(f32x4*)&qnew[(size_t)row * D_ + d] = out;
}

// ---------------------------------------------------------------------------
extern "C" void kernel_launch(void* const* d_in, const int* in_sizes, int n_in,
                              void* d_out, int out_size, void* d_ws, size_t ws_size,
                              hipStream_t stream) {
  const float* q           = (const float*)d_in[0];
  const float* kv          = (const float*)d_in[1];
  const float* qn_w        = (const float*)d_in[2];
  const float* kva_w       = (const float*)d_in[3];
  const float* kvi_w       = (const float*)d_in[4];
  const float* dn_w        = (const float*)d_in[5];
  const float* fn_w        = (const float*)d_in[6];
  const float* Wq          = (const float*)d_in[7];
  const float* bq          = (const float*)d_in[8];
  const float* Wk          = (const float*)d_in[9];
  const float* bk          = (const float*)d_in[10];
  const float* Wv          = (const float*)d_in[11];
  const float* bv          = (const float*)d_in[12];
  const float* Wo          = (const float*)d_in[13];
  const float* bo          = (const float*)d_in[14];
  const float* active_bias = (const float*)d_in[15];
  const float* inactive_b  = (const float*)d_in[16];
  const float* log_temp    = (const float*)d_in[17];
  const float* gate_attn   = (const float*)d_in[18];
  const float* gate_ffn    = (const float*)d_in[19];
  const float* Wr          = (const float*)d_in[20];
  const float* br          = (const float*)d_in[21];
  const float* W1          = (const float*)d_in[22];
  const float* b1          = (const float*)d_in[23];
  const float* W2          = (const float*)d_in[24];
  const float* b2          = (const float*)d_in[25];
  const int*   n_act       = (const int*)d_in[27];

  char* ws = (char*)d_ws;
  size_t off = 0;
  auto alloc = [&](size_t bytes) -> char* {
    char* p = ws + off;
    off = (off + bytes + 255) & ~(size_t)255;
    return p;
  };

  bf16_t* wqT  = (bf16_t*)alloc((size_t)D_ * D_ * 2);
  bf16_t* wkT  = (bf16_t*)alloc((size_t)D_ * D_ * 2);
  bf16_t* wvT  = (bf16_t*)alloc((size_t)D_ * D_ * 2);
  bf16_t* woT  = (bf16_t*)alloc((size_t)D_ * D_ * 2);
  bf16_t* w1T  = (bf16_t*)alloc((size_t)256 * D_ * 2);
  bf16_t* w2T  = (bf16_t*)alloc((size_t)D_ * 128 * 2);
  bf16_t* kvb  = (bf16_t*)alloc((size_t)B_ * TK_ * D_ * 2);
  bf16_t* xn   = (bf16_t*)alloc((size_t)B_ * TK_ * D_ * 2);
  bf16_t* qn   = (bf16_t*)alloc((size_t)B_ * TQ_ * D_ * 2);
  bf16_t* qp   = (bf16_t*)alloc((size_t)B_ * TQ_ * D_ * 2);
  bf16_t* kbuf = (bf16_t*)alloc((size_t)B_ * TK_ * D_ * 2);
  bf16_t* vt   = (bf16_t*)alloc((size_t)B_ * D_ * TK_ * 2);
  float*  probs = (float*)alloc((size_t)B_ * TK_ * NE_ * 4);
  bf16_t* attno = qn;
  bf16_t* proj  = qp;
  bf16_t* a2buf = kbuf;
  (void)ws_size; (void)in_sizes; (void)n_in; (void)out_size;

  float* q_new_out  = (float*)d_out;
  float* kv_new_out = (float*)d_out + (size_t)B_ * TQ_ * D_;

  dim3 tb(32, 8);
  FP4 fp;
  fp.in[0] = Wq; fp.in[1] = Wk; fp.in[2] = Wv; fp.in[3] = Wo;
  fp.out[0] = wqT; fp.out[1] = wkT; fp.out[2] = wvT; fp.out[3] = woT;
  fragorder4_kernel<<<dim3(32, 32, 4), tb, 0, stream>>>(fp);
  fragorder_kernel<<<dim3(2, 32, 4), tb, 0, stream>>>(W1, w1T, 64, D_ * 64, 64, 0, 131072);
  fragorder_kernel<<<dim3(32, 1, 4), tb, 0, stream>>>(W2, w2T, D_, 32 * D_, 0, 32, 16384);

  rms_kv_kernel<<<B_ * TK_, 256, 0, stream>>>(kv, kva_w, kvi_w, fn_w, active_bias,
                                              inactive_b, n_act, Wr, br, kvb, xn, probs);
  rms_q_kernel<<<B_ * TQ_, 256, 0, stream>>>(q, qn_w, qn);

  gemm64p_tn<1><<<dim3(B_ * TQ_ / 64, D_ / 128), 256, 0, stream>>>(qn, wqT, bq, qp, D_);
  gemm_kv<<<B_ * TK_ / 128 * (D_ / 128), 256, 0, stream>>>(kvb, wkT, wvT, bk, bv, kbuf, vt);

  attn_mfma_kernel<<<B_ * H_ * (TQ_ / 128), 256, 0, stream>>>(qp, kbuf, vt, attno, log_temp, n_act);

  gemm64p_tn<1><<<dim3(B_ * TQ_ / 64, D_ / 128), 256, 0, stream>>>(attno, woT, bo, proj, D_);
  delta_qnew_kernel<<<B_ * TQ_, 256, 0, stream>>>(proj, dn_w, q, gate_attn, q_new_out);

  gemm64p_h_act<<<dim3(B_ * TK_ / 64, 2), 256, 0, stream>>>(xn, w1T, b1, probs, a2buf);
  gemm_moe_p<<<dim3(B_ * TK_ / 128, D_ / 128), 256, 0, stream>>>(a2buf, w2T, kv, probs, b2,
                                                                 gate_ffn, kv_new_out);
}